// Round 15
// baseline (574.917 us; speedup 1.0000x reference)
//
#include <hip/hip_runtime.h>
#include <cstdint>
#include <cstddef>

// Problem constants
constexpr int BB      = 16;
constexpr int T_TEXT  = 512;
constexpr int HID     = 512;
constexpr int MAX_LEN = 2048;
constexpr int DP_CH   = 256;
constexpr int PP_CH   = 384;

typedef unsigned short u16;
typedef unsigned int   u32;
typedef short bf16x8 __attribute__((ext_vector_type(8)));
typedef float f32x4  __attribute__((ext_vector_type(4)));

// ---------------------------------------------------------------------------
// helpers
// ---------------------------------------------------------------------------
__device__ __forceinline__ void gload_lds16(const void* g, void* l) {
  // dest LDS address is wave-uniform base + lane*16 (hardware semantics)
  __builtin_amdgcn_global_load_lds(
      (const __attribute__((address_space(1))) u32*)g,
      (__attribute__((address_space(3))) u32*)l, 16, 0, 0);
}

template <int N> __device__ __forceinline__ void vm_wait() {
  if constexpr (N == 0)      asm volatile("s_waitcnt vmcnt(0)" ::: "memory");
  else if constexpr (N == 6) asm volatile("s_waitcnt vmcnt(6)" ::: "memory");
  else if constexpr (N == 9) asm volatile("s_waitcnt vmcnt(9)" ::: "memory");
  else static_assert(N == 0, "unsupported vmcnt literal");
}

// f32 -> bf16 round-to-nearest-even
__device__ __forceinline__ u16 f2bf(float v) {
  union { float f; u32 u; } a;
  a.f = v;
  u32 r = (a.u + 0x7FFFu + ((a.u >> 16) & 1u)) >> 16;
  return (u16)r;
}
__device__ __forceinline__ float bf2f(u16 h) {
  union { u32 u; float f; } a;
  a.u = (u32)h << 16;
  return a.f;
}

// ---------------------------------------------------------------------------
// Weight pack: w[(o*I + i)*KT + k] -> MFMA B-fragment order (bf16, RNE).
// packed u16 layout: [k][cb32][f][lane(64)][j(8)]
//   o = f*16 + (lane&15),  i = cb32*32 + (lane>>4)*8 + j
// (cb32 pairs are contiguous -> a 64-channel stage is one linear copy)
// ---------------------------------------------------------------------------
__global__ __launch_bounds__(256) void pack_w_k(const float* __restrict__ w,
                                                u16* __restrict__ p,
                                                int O, int I, int KT) {
  int NF  = O >> 4, NCB = I >> 5;
  int total = KT * NCB * NF * 64;
  int idx = blockIdx.x * 256 + threadIdx.x;
  if (idx >= total) return;
  int l  = idx & 63;
  int f  = (idx >> 6) % NF;
  int cb = ((idx >> 6) / NF) % NCB;
  int k  = (idx >> 6) / (NF * NCB);
  int o  = f * 16 + (l & 15);
  int ib = cb * 32 + (l >> 4) * 8;
  u16* pd = p + ((size_t)((k * NCB + cb) * NF + f)) * 512 + (size_t)l * 8;
#pragma unroll
  for (int j = 0; j < 8; ++j)
    pd[j] = f2bf(w[((size_t)o * I + ib + j) * KT + k]);
}

// ---------------------------------------------------------------------------
// DP kernel: 16x16x32 MFMA, proven full-drain sync (unchanged since r6).
// ---------------------------------------------------------------------------
template <int CIN, int COUT, int KT, int MT, int WM, int WN, int OPAD, bool F32OUT>
__global__ __launch_bounds__(WM * WN * 64)
void gemm_conv_ln(const u16* __restrict__ a, const u16* __restrict__ wp,
                  const float* __restrict__ bias, const float* __restrict__ gamma,
                  const float* __restrict__ beta,
                  u16* __restrict__ o, float* __restrict__ fo, int T) {
  constexpr int WAVES   = WM * WN;
  constexpr int THREADS = WAVES * 64;
  constexpr int RS    = MT + KT - 1;
  constexpr int NCB   = CIN / 32;
  constexpr int NF    = COUT / 16;
  constexpr int Mfr   = MT / (16 * WM);
  constexpr int Nfr   = NF / WN;
  constexpr int A_ONE = RS * 64;
  constexpr int B_ONE = NF * 1024;
  constexpr int B_OFF = 2 * A_ONE;
  constexpr int RED_OFF = B_OFF + 2 * B_ONE;
  constexpr int CPW = 4 * RS / WAVES;

  const int TpIn  = T + KT - 1;
  const int TpOut = T + 2 * OPAD;

  const int tid  = threadIdx.x;
  const int wave = tid >> 6;
  const int lane = tid & 63;
  const int sl   = lane & 15;
  const int q    = lane >> 4;
  const int wm   = wave / WN;
  const int wn   = wave % WN;
  const int waveM0 = wm * Mfr * 16;
  const int f0   = wn * Nfr;
  const int t0   = blockIdx.x * MT;
  const int b    = blockIdx.y;

  extern __shared__ __align__(16) char smem[];
  const u16* abase_g = a + ((size_t)b * TpIn + t0) * CIN;

  auto stageA = [&](int buf, int cb) {
    char* lbase = smem + buf * A_ONE;
#pragma unroll
    for (int j = 0; j < CPW; j += 64) {
      int c   = wave * CPW + j + lane;
      int qc  = c / RS;
      int row = c - qc * RS;
      if (j + lane < CPW)
        gload_lds16(abase_g + (size_t)row * CIN + cb * 32 + qc * 8,
                    lbase + (size_t)(wave * CPW + j) * 16);
    }
  };
  auto stageB = [&](int buf, int k, int cb) {
    const u16* src = wp + ((size_t)(k * NCB + cb) * NF) * 512;
    char* lbase = smem + B_OFF + buf * B_ONE;
    for (int i = tid; i < NF * 64; i += THREADS) {
      gload_lds16(src + (size_t)i * 8, lbase + (size_t)(i - lane) * 16);
    }
  };

  f32x4 acc[Mfr][Nfr];
#pragma unroll
  for (int mf = 0; mf < Mfr; ++mf)
#pragma unroll
    for (int nf = 0; nf < Nfr; ++nf) acc[mf][nf] = (f32x4)0.f;

  stageA(0, 0);
  stageB(0, 0, 0);
  asm volatile("s_waitcnt vmcnt(0)" ::: "memory");
  __syncthreads();
  int ab = 0, bb = 0;
  for (int cb = 0; cb < NCB; ++cb) {
    for (int k = 0; k < KT; ++k) {
      if (k + 1 < KT) {
        stageB(bb ^ 1, k + 1, cb);
      } else if (cb + 1 < NCB) {
        stageB(bb ^ 1, 0, cb + 1);
        stageA(ab ^ 1, cb + 1);
      }
      bf16x8 A[Mfr], Bf[Nfr];
      const char* ab_l = smem + ab * A_ONE;
#pragma unroll
      for (int mf = 0; mf < Mfr; ++mf) {
        int row = waveM0 + mf * 16 + sl + k;
        A[mf] = *(const bf16x8*)(ab_l + (q * RS + row) * 16);
      }
      const char* bb_l = smem + B_OFF + bb * B_ONE;
#pragma unroll
      for (int nf = 0; nf < Nfr; ++nf)
        Bf[nf] = *(const bf16x8*)(bb_l + (size_t)(f0 + nf) * 1024 + lane * 16);
#pragma unroll
      for (int nf = 0; nf < Nfr; ++nf)
#pragma unroll
        for (int mf = 0; mf < Mfr; ++mf)
          acc[mf][nf] = __builtin_amdgcn_mfma_f32_16x16x32_bf16(
              A[mf], Bf[nf], acc[mf][nf], 0, 0, 0);
      asm volatile("s_waitcnt vmcnt(0)" ::: "memory");
      __syncthreads();
      bb ^= 1;
      if (k == KT - 1) ab ^= 1;
    }
  }

  float bc[Nfr], gc[Nfr], btc[Nfr];
#pragma unroll
  for (int nf = 0; nf < Nfr; ++nf) {
    int col = (f0 + nf) * 16 + sl;
    bc[nf]  = bias[col];
    gc[nf]  = gamma[col];
    btc[nf] = beta[col];
  }

  float* reds  = (float*)(smem + RED_OFF);
  float* redss = reds + MT * WN;

#pragma unroll
  for (int mf = 0; mf < Mfr; ++mf) {
#pragma unroll
    for (int r = 0; r < 4; ++r) {
      float s = 0.f, ss2 = 0.f;
#pragma unroll
      for (int nf = 0; nf < Nfr; ++nf) {
        float x = acc[mf][nf][r] + bc[nf];
        x = fmaxf(x, 0.f);
        acc[mf][nf][r] = x;
        s += x;
        ss2 = fmaf(x, x, ss2);
      }
#pragma unroll
      for (int off = 1; off < 16; off <<= 1) {
        s   += __shfl_xor(s, off, 64);
        ss2 += __shfl_xor(ss2, off, 64);
      }
      if (sl == 0) {
        int rowb = waveM0 + mf * 16 + q * 4 + r;
        reds[rowb * WN + wn]  = s;
        redss[rowb * WN + wn] = ss2;
      }
    }
  }
  __syncthreads();

#pragma unroll
  for (int mf = 0; mf < Mfr; ++mf) {
#pragma unroll
    for (int r = 0; r < 4; ++r) {
      int rowb = waveM0 + mf * 16 + q * 4 + r;
      float s = 0.f, ss2 = 0.f;
#pragma unroll
      for (int w2 = 0; w2 < WN; ++w2) {
        s   += reds[rowb * WN + w2];
        ss2 += redss[rowb * WN + w2];
      }
      float mean = s * (1.f / COUT);
      float var  = ss2 * (1.f / COUT) - mean * mean;
      float rstd = 1.f / sqrtf(var + 1e-5f);
      int trow = t0 + rowb;
#pragma unroll
      for (int nf = 0; nf < Nfr; ++nf) {
        int col = (f0 + nf) * 16 + sl;
        float y = (acc[mf][nf][r] - mean) * rstd * gc[nf] + btc[nf];
        if constexpr (F32OUT) {
          fo[((size_t)b * T + trow) * COUT + col] = y;
        } else {
          o[((size_t)b * TpOut + OPAD + trow) * COUT + col] = f2bf(y);
        }
      }
    }
  }

  if constexpr (!F32OUT && OPAD > 0) {
    if (blockIdx.x == 0) {
      for (int i = tid; i < OPAD * COUT; i += THREADS) {
        o[(size_t)b * TpOut * COUT + i] = 0;
        o[((size_t)b * TpOut + OPAD + T) * COUT + i] = 0;
      }
    }
  }
}

constexpr int gemm_lds(int MT, int KT, int COUT, int WN_) {
  return 2 * (MT + KT - 1) * 64 + 2 * (COUT / 16) * 1024 + MT * WN_ * 8;
}

// ---------------------------------------------------------------------------
// Pitch kernel: BK=64 steps (2 packed cb32 panels per stage) on the
// r8-verified 2-barrier counted schedule with rescaled constants.
// Per step: stage next (B=6, or B+A=9 loads/wave) -> counted wait retires
// everything older (i.e. current step's data) -> barrier -> 20 ds_reads ->
// 48 MFMA -> barrier. Steps/layer: 60 -> 30.
// A LDS: chunk-major over 8 channel-octets, chunk c = qc*RS+row at c*16.
// ---------------------------------------------------------------------------
template <int CIN, int COUT, int KT, int MT, int WM, int WN, int OPAD>
__global__ __launch_bounds__(WM * WN * 64)
void gemm_conv_ln64(const u16* __restrict__ a, const u16* __restrict__ wp,
                    const float* __restrict__ bias, const float* __restrict__ gamma,
                    const float* __restrict__ beta,
                    u16* __restrict__ o, int T) {
  constexpr int WAVES   = WM * WN;
  constexpr int THREADS = WAVES * 64;
  constexpr int RS     = MT + KT - 1;      // 132
  constexpr int NCB    = CIN / 64;         // 64-ch chunks
  constexpr int NCB32  = CIN / 32;
  constexpr int NF     = COUT / 16;        // 24
  constexpr int Mfr    = MT / (16 * WM);   // 4
  constexpr int Nfr    = NF / WN;          // 6
  constexpr int A_ONE  = RS * 128;         // 8 octets x RS x 16B
  constexpr int B_ONE  = 2 * NF * 1024;    // 48KB (two cb32 panels)
  constexpr int B_OFF  = 2 * A_ONE;
  constexpr int RED_OFF = B_OFF + 2 * B_ONE;
  static_assert(CIN % 64 == 0, "BK=64 needs CIN multiple of 64");
  static_assert((8 * RS) % WAVES == 0, "A chunks split evenly per wave");
  static_assert((2 * NF * 64) % THREADS == 0, "B chunks split evenly");
  constexpr int CPW     = 8 * RS / WAVES;          // 132
  constexpr int A_INSTS = (CPW + 63) / 64;         // 3
  constexpr int VMB     = (2 * NF * 64) / THREADS; // 6
  constexpr int VMBA    = VMB + A_INSTS;           // 9

  const int TpIn  = T + KT - 1;
  const int TpOut = T + 2 * OPAD;

  const int tid  = threadIdx.x;
  const int wave = tid >> 6;
  const int lane = tid & 63;
  const int sl   = lane & 15;
  const int q    = lane >> 4;
  const int wm   = wave / WN;
  const int wn   = wave % WN;
  const int waveM0 = wm * Mfr * 16;
  const int f0   = wn * Nfr;
  const int t0   = blockIdx.x * MT;
  const int b    = blockIdx.y;

  extern __shared__ __align__(16) char smem[];
  const u16* abase_g = a + ((size_t)b * TpIn + t0) * CIN;

  // A staged chunk-major, per-wave partition (uniform A_INSTS insts/wave)
  auto stageA = [&](int buf, int cb) {
    char* lbase = smem + buf * A_ONE;
#pragma unroll
    for (int j = 0; j < CPW; j += 64) {
      int c   = wave * CPW + j + lane;
      int qc  = c / RS;
      int row = c - qc * RS;
      if (j + lane < CPW)
        gload_lds16(abase_g + (size_t)row * CIN + cb * 64 + qc * 8,
                    lbase + (size_t)(wave * CPW + j) * 16);
    }
  };
  // B staged once per block per (k, cb64): 2 contiguous cb32 panels (48KB)
  auto stageB = [&](int buf, int k, int cb) {
    const u16* src = wp + ((size_t)(k * NCB32 + 2 * cb) * NF) * 512;
    char* lbase = smem + B_OFF + buf * B_ONE;
#pragma unroll
    for (int i = tid; i < 2 * NF * 64; i += THREADS) {
      gload_lds16(src + (size_t)i * 8, lbase + (size_t)(i - lane) * 16);
    }
  };

  f32x4 acc[Mfr][Nfr];
#pragma unroll
  for (int mf = 0; mf < Mfr; ++mf)
#pragma unroll
    for (int nf = 0; nf < Nfr; ++nf) acc[mf][nf] = (f32x4)0.f;

  // prologue: A(0), B(0,0) — retired by the first step's counted wait
  stageA(0, 0);
  stageB(0, 0, 0);

  int ab = 0, bb = 0;
  for (int cb = 0; cb < NCB; ++cb) {
    for (int k = 0; k < KT; ++k) {
      // stage next step's buffers, then counted wait: retires everything
      // OLDER than the just-issued loads == current step's data.
      if (k + 1 < KT) {
        stageB(bb ^ 1, k + 1, cb);
        vm_wait<VMB>();
      } else if (cb + 1 < NCB) {
        stageB(bb ^ 1, 0, cb + 1);
        stageA(ab ^ 1, cb + 1);
        vm_wait<VMBA>();
      } else {
        vm_wait<0>();
      }
      __builtin_amdgcn_s_barrier();        // all waves' current data landed
      __builtin_amdgcn_sched_barrier(0);   // pin ds_reads below barrier

      bf16x8 A[Mfr][2], Bf[Nfr][2];
      const char* ab_l = smem + ab * A_ONE;
      const char* bb_l = smem + B_OFF + bb * B_ONE;
#pragma unroll
      for (int mf = 0; mf < Mfr; ++mf) {
        int row = waveM0 + mf * 16 + sl + k;
#pragma unroll
        for (int ks = 0; ks < 2; ++ks)
          A[mf][ks] = *(const bf16x8*)(ab_l + ((ks * 4 + q) * RS + row) * 16);
      }
#pragma unroll
      for (int nf = 0; nf < Nfr; ++nf)
#pragma unroll
        for (int ks = 0; ks < 2; ++ks)
          Bf[nf][ks] = *(const bf16x8*)(bb_l + (size_t)(ks * NF + f0 + nf) * 1024 + lane * 16);

      __builtin_amdgcn_s_setprio(1);
#pragma unroll
      for (int ks = 0; ks < 2; ++ks)
#pragma unroll
        for (int nf = 0; nf < Nfr; ++nf)
#pragma unroll
          for (int mf = 0; mf < Mfr; ++mf)
            acc[mf][nf] = __builtin_amdgcn_mfma_f32_16x16x32_bf16(
                A[mf][ks], Bf[nf][ks], acc[mf][nf], 0, 0, 0);
      __builtin_amdgcn_s_setprio(0);

      __builtin_amdgcn_sched_barrier(0);   // pin ds_reads above barrier
      __builtin_amdgcn_s_barrier();        // readers done before overwrite
      bb ^= 1;
      if (k == KT - 1) ab ^= 1;
    }
  }

  // ---- epilogue: bias + relu + channel-LN (cross-wave via LDS) ----
  float bc[Nfr], gc[Nfr], btc[Nfr];
#pragma unroll
  for (int nf = 0; nf < Nfr; ++nf) {
    int col = (f0 + nf) * 16 + sl;
    bc[nf]  = bias[col];
    gc[nf]  = gamma[col];
    btc[nf] = beta[col];
  }

  float* reds  = (float*)(smem + RED_OFF);   // [MT][WN]
  float* redss = reds + MT * WN;

#pragma unroll
  for (int mf = 0; mf < Mfr; ++mf) {
#pragma unroll
    for (int r = 0; r < 4; ++r) {
      float s = 0.f, ss2 = 0.f;
#pragma unroll
      for (int nf = 0; nf < Nfr; ++nf) {
        float x = acc[mf][nf][r] + bc[nf];
        x = fmaxf(x, 0.f);
        acc[mf][nf][r] = x;
        s += x;
        ss2 = fmaf(x, x, ss2);
      }
#pragma unroll
      for (int off = 1; off < 16; off <<= 1) {
        s   += __shfl_xor(s, off, 64);
        ss2 += __shfl_xor(ss2, off, 64);
      }
      if (sl == 0) {
        int rowb = waveM0 + mf * 16 + q * 4 + r;
        reds[rowb * WN + wn]  = s;
        redss[rowb * WN + wn] = ss2;
      }
    }
  }
  __syncthreads();

#pragma unroll
  for (int mf = 0; mf < Mfr; ++mf) {
#pragma unroll
    for (int r = 0; r < 4; ++r) {
      int rowb = waveM0 + mf * 16 + q * 4 + r;
      float s = 0.f, ss2 = 0.f;
#pragma unroll
      for (int w2 = 0; w2 < WN; ++w2) {
        s   += reds[rowb * WN + w2];
        ss2 += redss[rowb * WN + w2];
      }
      float mean = s * (1.f / COUT);
      float var  = ss2 * (1.f / COUT) - mean * mean;
      float rstd = 1.f / sqrtf(var + 1e-5f);
      int trow = t0 + rowb;
#pragma unroll
      for (int nf = 0; nf < Nfr; ++nf) {
        int col = (f0 + nf) * 16 + sl;
        float y = (acc[mf][nf][r] - mean) * rstd * gc[nf] + btc[nf];
        o[((size_t)b * TpOut + OPAD + trow) * COUT + col] = f2bf(y);
      }
    }
  }

  if constexpr (OPAD > 0) {
    if (blockIdx.x == 0) {   // zero the guard rows of this batch
      for (int i = tid; i < OPAD * COUT; i += THREADS) {
        o[(size_t)b * TpOut * COUT + i] = 0;
        o[((size_t)b * TpOut + OPAD + T) * COUT + i] = 0;
      }
    }
  }
}

constexpr int gemm_lds64(int MT, int KT, int COUT, int WN_) {
  return 2 * (MT + KT - 1) * 128 + 2 * (COUT / 16) * 2048 + MT * WN_ * 8;
}

// ---------------------------------------------------------------------------
// split x into padded bf16 plane [B][514][512] (PAD=1 guards zero)
// ---------------------------------------------------------------------------
__global__ __launch_bounds__(256) void split_x_k(const float* __restrict__ x,
                                                 u16* __restrict__ xb) {
  int b = blockIdx.y;
  int row = blockIdx.x * 4 + (threadIdx.x >> 6);
  int lane = threadIdx.x & 63;
  if (row >= T_TEXT + 2) return;
  size_t out = ((size_t)b * (T_TEXT + 2) + row) * HID;
  if (row == 0 || row == T_TEXT + 1) {
    for (int h = lane; h < HID; h += 64) xb[out + h] = 0;
    return;
  }
  const float* xr = x + ((size_t)b * T_TEXT + row - 1) * HID;
  for (int h = lane; h < HID; h += 64) xb[out + h] = f2bf(xr[h]);
}

// ---------------------------------------------------------------------------
// Duration head
// ---------------------------------------------------------------------------
__global__ __launch_bounds__(256) void dp_head_k(const float* __restrict__ h,
                                                 const float* __restrict__ w,
                                                 const float* __restrict__ b,
                                                 float* __restrict__ out) {
  int tid = threadIdx.x;
  int wv = tid >> 6, lane = tid & 63;
  int row = blockIdx.x * 4 + wv;
  const float* hr = h + (size_t)row * DP_CH;
  float s = 0.f;
  for (int c = lane; c < DP_CH; c += 64) s = fmaf(hr[c], w[c], s);
#pragma unroll
  for (int off = 1; off < 64; off <<= 1) s += __shfl_xor(s, off, 64);
  if (lane == 0) out[row] = s + b[0];
}

// ---------------------------------------------------------------------------
// cumsum of durations, mel_len
// ---------------------------------------------------------------------------
__global__ __launch_bounds__(512) void cumsum_k(const int* __restrict__ dur,
                                                int* __restrict__ cum,
                                                float* __restrict__ mel_len_out) {
  __shared__ int s[T_TEXT];
  int b = blockIdx.x, t = threadIdx.x;
  s[t] = dur[b * T_TEXT + t];
  __syncthreads();
  for (int off = 1; off < T_TEXT; off <<= 1) {
    int add = (t >= off) ? s[t - off] : 0;
    __syncthreads();
    s[t] += add;
    __syncthreads();
  }
  cum[b * T_TEXT + t] = s[t];
  if (t == T_TEXT - 1) mel_len_out[b] = (float)s[t];
}

// ---------------------------------------------------------------------------
// sinusoidal PE table, f32 (batch-independent; computed once instead of 16x)
// ---------------------------------------------------------------------------
__global__ __launch_bounds__(256) void pe_k(float* __restrict__ pe) {
  int f = blockIdx.x * 4 + (threadIdx.x >> 6);   // < MAX_LEN
  int lane = threadIdx.x & 63;
  float posf = (float)(f + 1);
  const float kfac = -0.03611898185f;  // -ln(10000)/255
  float* pr = pe + (size_t)f * HID;
  for (int h = lane; h < HID / 2; h += 64) {
    float inv = expf((float)h * kfac);
    float ang = posf * inv;
    float sv, cv;
    sincosf(ang, &sv, &cv);
    pr[h]           = sv;
    pr[h + HID / 2] = cv;
  }
}

// ---------------------------------------------------------------------------
// p = mel + alpha*pe -> padded bf16 plane [B][2052][512] (PAD=2 guards)
// ---------------------------------------------------------------------------
__global__ __launch_bounds__(256) void build_p_k(const float* __restrict__ x,
                                                 const int* __restrict__ cum,
                                                 const float* __restrict__ alpha_p,
                                                 const float* __restrict__ pe,
                                                 u16* __restrict__ pb) {
  __shared__ int cs[T_TEXT];
  int b = blockIdx.y, tid = threadIdx.x;
  for (int i = tid; i < T_TEXT; i += 256) cs[i] = cum[b * T_TEXT + i];
  __syncthreads();
  int row = blockIdx.x * 4 + (tid >> 6);
  int lane = tid & 63;
  if (row >= MAX_LEN + 4) return;
  size_t out = ((size_t)b * (MAX_LEN + 4) + row) * HID;
  if (row < 2 || row >= MAX_LEN + 2) {
    for (int h = lane; h < HID; h += 64) pb[out + h] = 0;
    return;
  }
  int f = row - 2;
  int lo = 0, hi = T_TEXT;
  while (lo < hi) {
    int mid = (lo + hi) >> 1;
    if (cs[mid] <= f) lo = mid + 1; else hi = mid;
  }
  int src = min(lo, T_TEXT - 1);
  float fm = (f < cs[T_TEXT - 1]) ? 1.f : 0.f;
  float alpha = alpha_p[0];
  const float* xr = x + ((size_t)b * T_TEXT + src) * HID;
  const float* pr = pe + (size_t)f * HID;
  for (int h = lane; h < HID; h += 64)
    pb[out + h] = f2bf(fmaf(alpha, pr[h], xr[h] * fm));
}

// ---------------------------------------------------------------------------
// Final head: pitch linear -> pred, bin search -> emb, out = mel + emb
// p is bf16 [B][2048][384] (unpadded).
// ---------------------------------------------------------------------------
__global__ __launch_bounds__(256) void final_head_k(
    const u16* __restrict__ p, const float* __restrict__ x,
    const int* __restrict__ cum, const float* __restrict__ lw,
    const float* __restrict__ lb, const float* __restrict__ bins,
    const float* __restrict__ emb, float* __restrict__ out0,
    float* __restrict__ pred) {
  __shared__ int cs[T_TEXT];
  int b = blockIdx.y, tid = threadIdx.x;
  for (int i = tid; i < T_TEXT; i += 256) cs[i] = cum[b * T_TEXT + i];
  __syncthreads();
  int wv = tid >> 6, lane = tid & 63;
  int f = blockIdx.x * 4 + wv;
  size_t row = (size_t)b * MAX_LEN + f;
  const u16* prr = p + row * PP_CH;
  float s0 = 0.f, s1 = 0.f;
  for (int c = lane; c < PP_CH; c += 64) {
    float v = bf2f(prr[c]);
    s0 = fmaf(v, lw[2 * c], s0);
    s1 = fmaf(v, lw[2 * c + 1], s1);
  }
#pragma unroll
  for (int off = 1; off < 64; off <<= 1) {
    s0 += __shfl_xor(s0, off, 64);
    s1 += __shfl_xor(s1, off, 64);
  }
  float p0 = s0 + lb[0];
  float p1 = s1 + lb[1];
  if (lane == 0) {
    pred[row * 2] = p0;
    pred[row * 2 + 1] = p1;
  }
  int lo = 0, hi = 255;
  while (lo < hi) {
    int mid = (lo + hi) >> 1;
    if (bins[mid] < p0) lo = mid + 1; else hi = mid;
  }
  int lo2 = 0, hi2 = T_TEXT;
  while (lo2 < hi2) {
    int mid = (lo2 + hi2) >> 1;
    if (cs[mid] <= f) lo2 = mid + 1; else hi2 = mid;
  }
  int src = min(lo2, T_TEXT - 1);
  float fm = (f < cs[T_TEXT - 1]) ? 1.f : 0.f;
  const float* xr = x + ((size_t)b * T_TEXT + src) * HID;
  const float* er = emb + (size_t)lo * HID;
  float* orow = out0 + row * HID;
  for (int h = lane; h < HID; h += 64) orow[h] = fmaf(xr[h], fm, er[h]);
}

// ---------------------------------------------------------------------------
extern "C" void kernel_launch(void* const* d_in, const int* in_sizes, int n_in,
                              void* d_out, int out_size, void* d_ws,
                              size_t ws_size, hipStream_t stream) {
  (void)in_sizes; (void)n_in; (void)out_size; (void)ws_size;

  const float* x          = (const float*)d_in[0];
  const int*   duration   = (const int*)d_in[1];
  const float* dp_w0      = (const float*)d_in[4];
  const float* dp_w1      = (const float*)d_in[5];
  const float* dp_b       = (const float*)d_in[6];
  const float* dp_g       = (const float*)d_in[7];
  const float* dp_beta    = (const float*)d_in[8];
  const float* dp_lin_w   = (const float*)d_in[9];
  const float* dp_lin_b   = (const float*)d_in[10];
  const float* pp_w0      = (const float*)d_in[11];
  const float* pp_w_rest  = (const float*)d_in[12];
  const float* pp_b       = (const float*)d_in[13];
  const float* pp_g       = (const float*)d_in[14];
  const float* pp_beta    = (const float*)d_in[15];
  const float* pp_lin_w   = (const float*)d_in[16];
  const float* pp_lin_b   = (const float*)d_in[17];
  const float* pos_alpha  = (const float*)d_in[18];
  const float* pitch_emb  = (const float*)d_in[19];
  const float* pitch_bins = (const float*)d_in[20];

  // ---- workspace layout (no aliasing) ----
  char* w8 = (char*)d_ws;
  size_t off = 0;
  auto alloc = [&](size_t bytes) {
    char* pp = w8 + off;
    off += (bytes + 255) & ~(size_t)255;
    return pp;
  };
  u16*   xb    = (u16*)alloc((size_t)BB * 514 * 512 * 2);
  u16*   dp1   = (u16*)alloc((size_t)BB * 514 * 256 * 2);
  float* dp2   = (float*)alloc((size_t)BB * 512 * 256 * 4);
  u16*   Pb    = (u16*)alloc((size_t)BB * 2052 * 512 * 2);
  u16*   ppA   = (u16*)alloc((size_t)BB * 2052 * 384 * 2);
  u16*   ppB   = (u16*)alloc((size_t)BB * 2052 * 384 * 2);
  u16*   pfin  = (u16*)alloc((size_t)BB * 2048 * 384 * 2);
  float* peT   = (float*)alloc((size_t)MAX_LEN * HID * 4);
  u16*   pwdp0 = (u16*)alloc((size_t)3 * 512 * 256 * 2);
  u16*   pwdp1 = (u16*)alloc((size_t)3 * 256 * 256 * 2);
  u16*   pwpp0 = (u16*)alloc((size_t)5 * 512 * 384 * 2);
  u16*   pwppr = (u16*)alloc((size_t)4 * 5 * 384 * 384 * 2);
  int*   cum   = (int*)alloc((size_t)BB * T_TEXT * 4);

  // output layout: out, log_dur, pitch_pred, mel_len
  float* out0       = (float*)d_out;
  float* log_dur    = out0 + (size_t)BB * MAX_LEN * HID;
  float* pitch_pred = log_dur + (size_t)BB * T_TEXT;
  float* mel_len    = pitch_pred + (size_t)BB * MAX_LEN * 2;

  // ---- weight packing ----
  auto pk = [&](const float* src, u16* dst, int O, int I, int KT) {
    int tot = KT * (I / 32) * (O / 16) * 64;
    pack_w_k<<<dim3((tot + 255) / 256), dim3(256), 0, stream>>>(src, dst, O, I, KT);
  };
  pk(dp_w0, pwdp0, 256, 512, 3);
  pk(dp_w1, pwdp1, 256, 256, 3);
  pk(pp_w0, pwpp0, 384, 512, 5);
  for (int l = 0; l < 4; ++l)
    pk(pp_w_rest + (size_t)l * 384 * 384 * 5,
       pwppr + (size_t)l * (5 * 384 * 384), 384, 384, 5);

  split_x_k<<<dim3(129, BB), dim3(256), 0, stream>>>(x, xb);
  cumsum_k<<<dim3(BB), dim3(512), 0, stream>>>(duration, cum, mel_len);
  pe_k<<<dim3(MAX_LEN / 4), dim3(256), 0, stream>>>(peT);

  // ---- duration predictor (MT=64, 4 waves 2x2, proven full-drain sync) ----
  constexpr int LDS_DP = gemm_lds(64, 3, 256, 2);
  gemm_conv_ln<512, 256, 3, 64, 2, 2, 1, false>
      <<<dim3(8, BB), dim3(256), LDS_DP, stream>>>(
          xb, pwdp0, dp_b, dp_g, dp_beta, dp1, nullptr, T_TEXT);
  gemm_conv_ln<256, 256, 3, 64, 2, 2, 1, true>
      <<<dim3(8, BB), dim3(256), LDS_DP, stream>>>(
          dp1, pwdp1, dp_b + 256, dp_g + 256, dp_beta + 256,
          nullptr, dp2, T_TEXT);
  dp_head_k<<<dim3(BB * T_TEXT / 4), dim3(256), 0, stream>>>(dp2, dp_lin_w,
                                                             dp_lin_b, log_dur);

  // ---- length regulator ----
  build_p_k<<<dim3(513, BB), dim3(256), 0, stream>>>(x, cum, pos_alpha, peT, Pb);

  // ---- pitch predictor (5 layers, MT=128, 8 waves 2x4, BK=64 steps) ----
  constexpr int LDS_PP = gemm_lds64(128, 5, 384, 4);   // 133 KB
  gemm_conv_ln64<512, 384, 5, 128, 2, 4, 2>
      <<<dim3(16, BB), dim3(512), LDS_PP, stream>>>(
          Pb, pwpp0, pp_b, pp_g, pp_beta, ppA, MAX_LEN);
  gemm_conv_ln64<384, 384, 5, 128, 2, 4, 2>
      <<<dim3(16, BB), dim3(512), LDS_PP, stream>>>(
          ppA, pwppr + 0 * (5 * 384 * 384),
          pp_b + 384, pp_g + 384, pp_beta + 384, ppB, MAX_LEN);
  gemm_conv_ln64<384, 384, 5, 128, 2, 4, 2>
      <<<dim3(16, BB), dim3(512), LDS_PP, stream>>>(
          ppB, pwppr + 1 * (5 * 384 * 384),
          pp_b + 768, pp_g + 768, pp_beta + 768, ppA, MAX_LEN);
  gemm_conv_ln64<384, 384, 5, 128, 2, 4, 2>
      <<<dim3(16, BB), dim3(512), LDS_PP, stream>>>(
          ppA, pwppr + 2 * (5 * 384 * 384),
          pp_b + 1152, pp_g + 1152, pp_beta + 1152, ppB, MAX_LEN);
  gemm_conv_ln64<384, 384, 5, 128, 2, 4, 0>
      <<<dim3(16, BB), dim3(512), LDS_PP, stream>>>(
          ppB, pwppr + 3 * (5 * 384 * 384),
          pp_b + 1536, pp_g + 1536, pp_beta + 1536, pfin, MAX_LEN);

  // ---- final fused head ----
  final_head_k<<<dim3(MAX_LEN / 4, BB), dim3(256), 0, stream>>>(
      pfin, x, cum, pp_lin_w, pp_lin_b, pitch_bins, pitch_emb, out0, pitch_pred);
}

// Round 16
// 412.105 us; speedup vs baseline: 1.3951x; 1.3951x over previous
//
#include <hip/hip_runtime.h>
#include <cstdint>
#include <cstddef>

// Problem constants
constexpr int BB      = 16;
constexpr int T_TEXT  = 512;
constexpr int HID     = 512;
constexpr int MAX_LEN = 2048;
constexpr int DP_CH   = 256;
constexpr int PP_CH   = 384;

typedef unsigned short u16;
typedef unsigned int   u32;
typedef short bf16x8 __attribute__((ext_vector_type(8)));
typedef float f32x4  __attribute__((ext_vector_type(4)));

// ---------------------------------------------------------------------------
// helpers
// ---------------------------------------------------------------------------
__device__ __forceinline__ void gload_lds16(const void* g, void* l) {
  // dest LDS address is wave-uniform base + lane*16 (hardware semantics)
  __builtin_amdgcn_global_load_lds(
      (const __attribute__((address_space(1))) u32*)g,
      (__attribute__((address_space(3))) u32*)l, 16, 0, 0);
}

template <int N> __device__ __forceinline__ void vm_wait() {
  if constexpr (N == 0)      asm volatile("s_waitcnt vmcnt(0)" ::: "memory");
  else if constexpr (N == 3) asm volatile("s_waitcnt vmcnt(3)" ::: "memory");
  else if constexpr (N == 5) asm volatile("s_waitcnt vmcnt(5)" ::: "memory");
  else static_assert(N == 0, "unsupported vmcnt literal");
}

// f32 -> bf16 round-to-nearest-even
__device__ __forceinline__ u16 f2bf(float v) {
  union { float f; u32 u; } a;
  a.f = v;
  u32 r = (a.u + 0x7FFFu + ((a.u >> 16) & 1u)) >> 16;
  return (u16)r;
}
__device__ __forceinline__ float bf2f(u16 h) {
  union { u32 u; float f; } a;
  a.u = (u32)h << 16;
  return a.f;
}

// ---------------------------------------------------------------------------
// Weight pack: w[(o*I + i)*KT + k] -> MFMA B-fragment order (bf16, RNE).
// packed u16 layout: [k][cb][f][lane(64)][j(8)]
//   o = f*16 + (lane&15),  i = cb*32 + (lane>>4)*8 + j
// ---------------------------------------------------------------------------
__global__ __launch_bounds__(256) void pack_w_k(const float* __restrict__ w,
                                                u16* __restrict__ p,
                                                int O, int I, int KT) {
  int NF  = O >> 4, NCB = I >> 5;
  int total = KT * NCB * NF * 64;
  int idx = blockIdx.x * 256 + threadIdx.x;
  if (idx >= total) return;
  int l  = idx & 63;
  int f  = (idx >> 6) % NF;
  int cb = ((idx >> 6) / NF) % NCB;
  int k  = (idx >> 6) / (NF * NCB);
  int o  = f * 16 + (l & 15);
  int ib = cb * 32 + (l >> 4) * 8;
  u16* pd = p + ((size_t)((k * NCB + cb) * NF + f)) * 512 + (size_t)l * 8;
#pragma unroll
  for (int j = 0; j < 8; ++j)
    pd[j] = f2bf(w[((size_t)o * I + ib + j) * KT + k]);
}

// ---------------------------------------------------------------------------
// Fused conv1d + bias + ReLU + channel-LN as bf16 MFMA GEMM.
// A in LDS (double-buffered per 32-ch chunk, chunk-major).
// PIPE=false (DP): proven full-drain single-step loop, 2 B buffers.
// PIPE=true (pitch): 3-deep counted pipeline, ONE barrier per step.
//   KT B-buffers (buf == tap, reuse distance = one full cb = 5 steps).
//   stageB(s+2) issued in phase s; end-of-phase wait vmcnt(3) retires
//   exactly B(s+1) (issued 2 phases back -> landed, wait ~free);
//   vmcnt(5) at cb-boundary phases keeps the fresh A prefetch in flight;
//   vmcnt(0) only at the tail.
// ---------------------------------------------------------------------------
template <int CIN, int COUT, int KT, int MT, int WM, int WN, int OPAD,
          bool F32OUT, bool PIPE>
__global__ __launch_bounds__(WM * WN * 64)
void gemm_conv_ln(const u16* __restrict__ a, const u16* __restrict__ wp,
                  const float* __restrict__ bias, const float* __restrict__ gamma,
                  const float* __restrict__ beta,
                  u16* __restrict__ o, float* __restrict__ fo, int T) {
  constexpr int WAVES   = WM * WN;
  constexpr int THREADS = WAVES * 64;
  constexpr int RS    = MT + KT - 1;      // staged input rows
  constexpr int NCB   = CIN / 32;
  constexpr int NF    = COUT / 16;
  constexpr int Mfr   = MT / (16 * WM);
  constexpr int Nfr   = NF / WN;
  constexpr int A_ONE = RS * 64;          // bytes, one A buffer (RS*4 chunks x 16B)
  constexpr int B_ONE = NF * 1024;        // bytes, one B buffer (NF frags x 1KB)
  constexpr int B_OFF = 2 * A_ONE;
  constexpr int NBUFB = PIPE ? KT : 2;
  constexpr int RED_OFF = B_OFF + NBUFB * B_ONE;
  constexpr int NSTEPS = NCB * KT;
  static_assert(MT % (16 * WM) == 0 && NF % WN == 0, "tiling");
  static_assert((4 * RS) % WAVES == 0, "A chunks split evenly per wave");
  static_assert((NF * 64) % THREADS == 0, "B chunks split evenly");
  constexpr int CPW = 4 * RS / WAVES;     // A chunks per wave

  const int TpIn  = T + KT - 1;
  const int TpOut = T + 2 * OPAD;

  const int tid  = threadIdx.x;
  const int wave = tid >> 6;
  const int lane = tid & 63;
  const int sl   = lane & 15;
  const int q    = lane >> 4;
  const int wm   = wave / WN;
  const int wn   = wave % WN;
  const int waveM0 = wm * Mfr * 16;
  const int f0   = wn * Nfr;
  const int t0   = blockIdx.x * MT;
  const int b    = blockIdx.y;

  extern __shared__ __align__(16) char smem[];

  const u16* abase_g = a + ((size_t)b * TpIn + t0) * CIN;

  // A staged chunk-major, per-wave partition: chunk c = qc*RS + row @ c*16
  auto stageA = [&](int buf, int cb) {
    char* lbase = smem + buf * A_ONE;
#pragma unroll
    for (int j = 0; j < CPW; j += 64) {
      int c   = wave * CPW + j + lane;
      int qc  = c / RS;
      int row = c - qc * RS;
      if (j + lane < CPW)
        gload_lds16(abase_g + (size_t)row * CIN + cb * 32 + qc * 8,
                    lbase + (size_t)(wave * CPW + j) * 16);
    }
  };
  // B staged once per block per (k,cb), packed-linear
  auto stageB = [&](int buf, int k, int cb) {
    const u16* src = wp + ((size_t)(k * NCB + cb) * NF) * 512;
    char* lbase = smem + B_OFF + buf * B_ONE;
#pragma unroll
    for (int i = tid; i < NF * 64; i += THREADS) {
      gload_lds16(src + (size_t)i * 8, lbase + (size_t)(i - lane) * 16);
    }
  };

  f32x4 acc[Mfr][Nfr];
#pragma unroll
  for (int mf = 0; mf < Mfr; ++mf)
#pragma unroll
    for (int nf = 0; nf < Nfr; ++nf) acc[mf][nf] = (f32x4)0.f;

  if constexpr (PIPE) {
    // prologue: A(0), B(0), B(1); wait keeps only B(1) in flight
    stageA(0, 0);
    stageB(0, 0, 0);
    stageB(1 % KT, 1 % KT, 0);
    vm_wait<3>();
    __builtin_amdgcn_s_barrier();

    for (int cb = 0; cb < NCB; ++cb) {
      const char* ab_l = smem + (cb & 1) * A_ONE;
#pragma unroll
      for (int j = 0; j < KT; ++j) {
        const int s = cb * KT + j;
        __builtin_amdgcn_sched_barrier(0);   // pin reads below prev barrier

        bf16x8 A[Mfr], Bf[Nfr];
        const char* bb_l = smem + B_OFF + j * B_ONE;
#pragma unroll
        for (int mf = 0; mf < Mfr; ++mf) {
          int row = waveM0 + mf * 16 + sl + j;
          A[mf] = *(const bf16x8*)(ab_l + (q * RS + row) * 16);
        }
#pragma unroll
        for (int nf = 0; nf < Nfr; ++nf)
          Bf[nf] = *(const bf16x8*)(bb_l + (size_t)(f0 + nf) * 1024 + lane * 16);

        const bool boundary = (j == 0 && cb + 1 < NCB);
        if (boundary) stageA((cb + 1) & 1, cb + 1);
        if (s + 2 < NSTEPS) {
          const int s2 = s + 2;
          stageB(s2 % KT, s2 % KT, s2 / KT);
        }

        __builtin_amdgcn_s_setprio(1);
#pragma unroll
        for (int nf = 0; nf < Nfr; ++nf)
#pragma unroll
          for (int mf = 0; mf < Mfr; ++mf)
            acc[mf][nf] = __builtin_amdgcn_mfma_f32_16x16x32_bf16(
                A[mf], Bf[nf], acc[mf][nf], 0, 0, 0);
        __builtin_amdgcn_s_setprio(0);

        __builtin_amdgcn_sched_barrier(0);   // pin reads above the wait
        if (s + 2 < NSTEPS) {
          if (boundary) vm_wait<5>();        // retire B(s+1), keep A+B(s+2)
          else          vm_wait<3>();        // retire B(s+1), keep B(s+2)
        } else {
          vm_wait<0>();                      // tail drain
        }
        __builtin_amdgcn_s_barrier();        // single gate per step
      }
    }
  } else {
    // proven full-drain single-step loop (B bufs 0/1)
    stageA(0, 0);
    stageB(0, 0, 0);
    asm volatile("s_waitcnt vmcnt(0)" ::: "memory");
    __syncthreads();
    int ab = 0, bb = 0;
    for (int cb = 0; cb < NCB; ++cb) {
      for (int k = 0; k < KT; ++k) {
        if (k + 1 < KT) {
          stageB(bb ^ 1, k + 1, cb);
        } else if (cb + 1 < NCB) {
          stageB(bb ^ 1, 0, cb + 1);
          stageA(ab ^ 1, cb + 1);
        }
        bf16x8 A[Mfr], Bf[Nfr];
        const char* ab_l = smem + ab * A_ONE;
#pragma unroll
        for (int mf = 0; mf < Mfr; ++mf) {
          int row = waveM0 + mf * 16 + sl + k;
          A[mf] = *(const bf16x8*)(ab_l + (q * RS + row) * 16);
        }
        const char* bb_l = smem + B_OFF + bb * B_ONE;
#pragma unroll
        for (int nf = 0; nf < Nfr; ++nf)
          Bf[nf] = *(const bf16x8*)(bb_l + (size_t)(f0 + nf) * 1024 + lane * 16);
#pragma unroll
        for (int nf = 0; nf < Nfr; ++nf)
#pragma unroll
          for (int mf = 0; mf < Mfr; ++mf)
            acc[mf][nf] = __builtin_amdgcn_mfma_f32_16x16x32_bf16(
                A[mf], Bf[nf], acc[mf][nf], 0, 0, 0);
        asm volatile("s_waitcnt vmcnt(0)" ::: "memory");
        __syncthreads();
        bb ^= 1;
        if (k == KT - 1) ab ^= 1;
      }
    }
  }

  // ---- epilogue: bias + relu + channel-LN (cross-wave via LDS) ----
  float bc[Nfr], gc[Nfr], btc[Nfr];
#pragma unroll
  for (int nf = 0; nf < Nfr; ++nf) {
    int col = (f0 + nf) * 16 + sl;
    bc[nf]  = bias[col];
    gc[nf]  = gamma[col];
    btc[nf] = beta[col];
  }

  float* reds  = (float*)(smem + RED_OFF);   // [MT][WN]
  float* redss = reds + MT * WN;

#pragma unroll
  for (int mf = 0; mf < Mfr; ++mf) {
#pragma unroll
    for (int r = 0; r < 4; ++r) {
      float s = 0.f, ss2 = 0.f;
#pragma unroll
      for (int nf = 0; nf < Nfr; ++nf) {
        float x = acc[mf][nf][r] + bc[nf];
        x = fmaxf(x, 0.f);
        acc[mf][nf][r] = x;
        s += x;
        ss2 = fmaf(x, x, ss2);
      }
#pragma unroll
      for (int off = 1; off < 16; off <<= 1) {
        s   += __shfl_xor(s, off, 64);
        ss2 += __shfl_xor(ss2, off, 64);
      }
      if (sl == 0) {
        int rowb = waveM0 + mf * 16 + q * 4 + r;
        reds[rowb * WN + wn]  = s;
        redss[rowb * WN + wn] = ss2;
      }
    }
  }
  __syncthreads();

#pragma unroll
  for (int mf = 0; mf < Mfr; ++mf) {
#pragma unroll
    for (int r = 0; r < 4; ++r) {
      int rowb = waveM0 + mf * 16 + q * 4 + r;
      float s = 0.f, ss2 = 0.f;
#pragma unroll
      for (int w2 = 0; w2 < WN; ++w2) {
        s   += reds[rowb * WN + w2];
        ss2 += redss[rowb * WN + w2];
      }
      float mean = s * (1.f / COUT);
      float var  = ss2 * (1.f / COUT) - mean * mean;
      float rstd = 1.f / sqrtf(var + 1e-5f);
      int trow = t0 + rowb;
#pragma unroll
      for (int nf = 0; nf < Nfr; ++nf) {
        int col = (f0 + nf) * 16 + sl;
        float y = (acc[mf][nf][r] - mean) * rstd * gc[nf] + btc[nf];
        if constexpr (F32OUT) {
          fo[((size_t)b * T + trow) * COUT + col] = y;
        } else {
          o[((size_t)b * TpOut + OPAD + trow) * COUT + col] = f2bf(y);
        }
      }
    }
  }

  if constexpr (!F32OUT && OPAD > 0) {
    if (blockIdx.x == 0) {   // zero the guard rows of this batch
      for (int i = tid; i < OPAD * COUT; i += THREADS) {
        o[(size_t)b * TpOut * COUT + i] = 0;
        o[((size_t)b * TpOut + OPAD + T) * COUT + i] = 0;
      }
    }
  }
}

constexpr int gemm_lds(int MT, int KT, int COUT, int WN_, int nbufb) {
  return 2 * (MT + KT - 1) * 64 + nbufb * (COUT / 16) * 1024 + MT * WN_ * 8;
}

// ---------------------------------------------------------------------------
// split x into padded bf16 plane [B][514][512] (PAD=1 guards zero)
// ---------------------------------------------------------------------------
__global__ __launch_bounds__(256) void split_x_k(const float* __restrict__ x,
                                                 u16* __restrict__ xb) {
  int b = blockIdx.y;
  int row = blockIdx.x * 4 + (threadIdx.x >> 6);
  int lane = threadIdx.x & 63;
  if (row >= T_TEXT + 2) return;
  size_t out = ((size_t)b * (T_TEXT + 2) + row) * HID;
  if (row == 0 || row == T_TEXT + 1) {
    for (int h = lane; h < HID; h += 64) xb[out + h] = 0;
    return;
  }
  const float* xr = x + ((size_t)b * T_TEXT + row - 1) * HID;
  for (int h = lane; h < HID; h += 64) xb[out + h] = f2bf(xr[h]);
}

// ---------------------------------------------------------------------------
// Duration head
// ---------------------------------------------------------------------------
__global__ __launch_bounds__(256) void dp_head_k(const float* __restrict__ h,
                                                 const float* __restrict__ w,
                                                 const float* __restrict__ b,
                                                 float* __restrict__ out) {
  int tid = threadIdx.x;
  int wv = tid >> 6, lane = tid & 63;
  int row = blockIdx.x * 4 + wv;
  const float* hr = h + (size_t)row * DP_CH;
  float s = 0.f;
  for (int c = lane; c < DP_CH; c += 64) s = fmaf(hr[c], w[c], s);
#pragma unroll
  for (int off = 1; off < 64; off <<= 1) s += __shfl_xor(s, off, 64);
  if (lane == 0) out[row] = s + b[0];
}

// ---------------------------------------------------------------------------
// cumsum of durations, mel_len
// ---------------------------------------------------------------------------
__global__ __launch_bounds__(512) void cumsum_k(const int* __restrict__ dur,
                                                int* __restrict__ cum,
                                                float* __restrict__ mel_len_out) {
  __shared__ int s[T_TEXT];
  int b = blockIdx.x, t = threadIdx.x;
  s[t] = dur[b * T_TEXT + t];
  __syncthreads();
  for (int off = 1; off < T_TEXT; off <<= 1) {
    int add = (t >= off) ? s[t - off] : 0;
    __syncthreads();
    s[t] += add;
    __syncthreads();
  }
  cum[b * T_TEXT + t] = s[t];
  if (t == T_TEXT - 1) mel_len_out[b] = (float)s[t];
}

// ---------------------------------------------------------------------------
// sinusoidal PE table, f32 (batch-independent; computed once instead of 16x)
// ---------------------------------------------------------------------------
__global__ __launch_bounds__(256) void pe_k(float* __restrict__ pe) {
  int f = blockIdx.x * 4 + (threadIdx.x >> 6);   // < MAX_LEN
  int lane = threadIdx.x & 63;
  float posf = (float)(f + 1);
  const float kfac = -0.03611898185f;  // -ln(10000)/255
  float* pr = pe + (size_t)f * HID;
  for (int h = lane; h < HID / 2; h += 64) {
    float inv = expf((float)h * kfac);
    float ang = posf * inv;
    float sv, cv;
    sincosf(ang, &sv, &cv);
    pr[h]           = sv;
    pr[h + HID / 2] = cv;
  }
}

// ---------------------------------------------------------------------------
// p = mel + alpha*pe -> padded bf16 plane [B][2052][512] (PAD=2 guards)
// ---------------------------------------------------------------------------
__global__ __launch_bounds__(256) void build_p_k(const float* __restrict__ x,
                                                 const int* __restrict__ cum,
                                                 const float* __restrict__ alpha_p,
                                                 const float* __restrict__ pe,
                                                 u16* __restrict__ pb) {
  __shared__ int cs[T_TEXT];
  int b = blockIdx.y, tid = threadIdx.x;
  for (int i = tid; i < T_TEXT; i += 256) cs[i] = cum[b * T_TEXT + i];
  __syncthreads();
  int row = blockIdx.x * 4 + (tid >> 6);
  int lane = tid & 63;
  if (row >= MAX_LEN + 4) return;
  size_t out = ((size_t)b * (MAX_LEN + 4) + row) * HID;
  if (row < 2 || row >= MAX_LEN + 2) {
    for (int h = lane; h < HID; h += 64) pb[out + h] = 0;
    return;
  }
  int f = row - 2;
  int lo = 0, hi = T_TEXT;
  while (lo < hi) {
    int mid = (lo + hi) >> 1;
    if (cs[mid] <= f) lo = mid + 1; else hi = mid;
  }
  int src = min(lo, T_TEXT - 1);
  float fm = (f < cs[T_TEXT - 1]) ? 1.f : 0.f;
  float alpha = alpha_p[0];
  const float* xr = x + ((size_t)b * T_TEXT + src) * HID;
  const float* pr = pe + (size_t)f * HID;
  for (int h = lane; h < HID; h += 64)
    pb[out + h] = f2bf(fmaf(alpha, pr[h], xr[h] * fm));
}

// ---------------------------------------------------------------------------
// Final head: pitch linear -> pred, bin search -> emb, out = mel + emb
// p is bf16 [B][2048][384] (unpadded).
// ---------------------------------------------------------------------------
__global__ __launch_bounds__(256) void final_head_k(
    const u16* __restrict__ p, const float* __restrict__ x,
    const int* __restrict__ cum, const float* __restrict__ lw,
    const float* __restrict__ lb, const float* __restrict__ bins,
    const float* __restrict__ emb, float* __restrict__ out0,
    float* __restrict__ pred) {
  __shared__ int cs[T_TEXT];
  int b = blockIdx.y, tid = threadIdx.x;
  for (int i = tid; i < T_TEXT; i += 256) cs[i] = cum[b * T_TEXT + i];
  __syncthreads();
  int wv = tid >> 6, lane = tid & 63;
  int f = blockIdx.x * 4 + wv;
  size_t row = (size_t)b * MAX_LEN + f;
  const u16* prr = p + row * PP_CH;
  float s0 = 0.f, s1 = 0.f;
  for (int c = lane; c < PP_CH; c += 64) {
    float v = bf2f(prr[c]);
    s0 = fmaf(v, lw[2 * c], s0);
    s1 = fmaf(v, lw[2 * c + 1], s1);
  }
#pragma unroll
  for (int off = 1; off < 64; off <<= 1) {
    s0 += __shfl_xor(s0, off, 64);
    s1 += __shfl_xor(s1, off, 64);
  }
  float p0 = s0 + lb[0];
  float p1 = s1 + lb[1];
  if (lane == 0) {
    pred[row * 2] = p0;
    pred[row * 2 + 1] = p1;
  }
  int lo = 0, hi = 255;
  while (lo < hi) {
    int mid = (lo + hi) >> 1;
    if (bins[mid] < p0) lo = mid + 1; else hi = mid;
  }
  int lo2 = 0, hi2 = T_TEXT;
  while (lo2 < hi2) {
    int mid = (lo2 + hi2) >> 1;
    if (cs[mid] <= f) lo2 = mid + 1; else hi2 = mid;
  }
  int src = min(lo2, T_TEXT - 1);
  float fm = (f < cs[T_TEXT - 1]) ? 1.f : 0.f;
  const float* xr = x + ((size_t)b * T_TEXT + src) * HID;
  const float* er = emb + (size_t)lo * HID;
  float* orow = out0 + row * HID;
  for (int h = lane; h < HID; h += 64) orow[h] = fmaf(xr[h], fm, er[h]);
}

// ---------------------------------------------------------------------------
extern "C" void kernel_launch(void* const* d_in, const int* in_sizes, int n_in,
                              void* d_out, int out_size, void* d_ws,
                              size_t ws_size, hipStream_t stream) {
  (void)in_sizes; (void)n_in; (void)out_size; (void)ws_size;

  const float* x          = (const float*)d_in[0];
  const int*   duration   = (const int*)d_in[1];
  const float* dp_w0      = (const float*)d_in[4];
  const float* dp_w1      = (const float*)d_in[5];
  const float* dp_b       = (const float*)d_in[6];
  const float* dp_g       = (const float*)d_in[7];
  const float* dp_beta    = (const float*)d_in[8];
  const float* dp_lin_w   = (const float*)d_in[9];
  const float* dp_lin_b   = (const float*)d_in[10];
  const float* pp_w0      = (const float*)d_in[11];
  const float* pp_w_rest  = (const float*)d_in[12];
  const float* pp_b       = (const float*)d_in[13];
  const float* pp_g       = (const float*)d_in[14];
  const float* pp_beta    = (const float*)d_in[15];
  const float* pp_lin_w   = (const float*)d_in[16];
  const float* pp_lin_b   = (const float*)d_in[17];
  const float* pos_alpha  = (const float*)d_in[18];
  const float* pitch_emb  = (const float*)d_in[19];
  const float* pitch_bins = (const float*)d_in[20];

  // ---- workspace layout (no aliasing) ----
  char* w8 = (char*)d_ws;
  size_t off = 0;
  auto alloc = [&](size_t bytes) {
    char* pp = w8 + off;
    off += (bytes + 255) & ~(size_t)255;
    return pp;
  };
  u16*   xb    = (u16*)alloc((size_t)BB * 514 * 512 * 2);
  u16*   dp1   = (u16*)alloc((size_t)BB * 514 * 256 * 2);
  float* dp2   = (float*)alloc((size_t)BB * 512 * 256 * 4);
  u16*   Pb    = (u16*)alloc((size_t)BB * 2052 * 512 * 2);
  u16*   ppA   = (u16*)alloc((size_t)BB * 2052 * 384 * 2);
  u16*   ppB   = (u16*)alloc((size_t)BB * 2052 * 384 * 2);
  u16*   pfin  = (u16*)alloc((size_t)BB * 2048 * 384 * 2);
  float* peT   = (float*)alloc((size_t)MAX_LEN * HID * 4);
  u16*   pwdp0 = (u16*)alloc((size_t)3 * 512 * 256 * 2);
  u16*   pwdp1 = (u16*)alloc((size_t)3 * 256 * 256 * 2);
  u16*   pwpp0 = (u16*)alloc((size_t)5 * 512 * 384 * 2);
  u16*   pwppr = (u16*)alloc((size_t)4 * 5 * 384 * 384 * 2);
  int*   cum   = (int*)alloc((size_t)BB * T_TEXT * 4);

  // output layout: out, log_dur, pitch_pred, mel_len
  float* out0       = (float*)d_out;
  float* log_dur    = out0 + (size_t)BB * MAX_LEN * HID;
  float* pitch_pred = log_dur + (size_t)BB * T_TEXT;
  float* mel_len    = pitch_pred + (size_t)BB * MAX_LEN * 2;

  // ---- weight packing ----
  auto pk = [&](const float* src, u16* dst, int O, int I, int KT) {
    int tot = KT * (I / 32) * (O / 16) * 64;
    pack_w_k<<<dim3((tot + 255) / 256), dim3(256), 0, stream>>>(src, dst, O, I, KT);
  };
  pk(dp_w0, pwdp0, 256, 512, 3);
  pk(dp_w1, pwdp1, 256, 256, 3);
  pk(pp_w0, pwpp0, 384, 512, 5);
  for (int l = 0; l < 4; ++l)
    pk(pp_w_rest + (size_t)l * 384 * 384 * 5,
       pwppr + (size_t)l * (5 * 384 * 384), 384, 384, 5);

  split_x_k<<<dim3(129, BB), dim3(256), 0, stream>>>(x, xb);
  cumsum_k<<<dim3(BB), dim3(512), 0, stream>>>(duration, cum, mel_len);
  pe_k<<<dim3(MAX_LEN / 4), dim3(256), 0, stream>>>(peT);

  // ---- duration predictor (MT=64, 4 waves 2x2, proven full-drain sync) ----
  constexpr int LDS_DP = gemm_lds(64, 3, 256, 2, 2);
  gemm_conv_ln<512, 256, 3, 64, 2, 2, 1, false, false>
      <<<dim3(8, BB), dim3(256), LDS_DP, stream>>>(
          xb, pwdp0, dp_b, dp_g, dp_beta, dp1, nullptr, T_TEXT);
  gemm_conv_ln<256, 256, 3, 64, 2, 2, 1, true, false>
      <<<dim3(8, BB), dim3(256), LDS_DP, stream>>>(
          dp1, pwdp1, dp_b + 256, dp_g + 256, dp_beta + 256,
          nullptr, dp2, T_TEXT);
  dp_head_k<<<dim3(BB * T_TEXT / 4), dim3(256), 0, stream>>>(dp2, dp_lin_w,
                                                             dp_lin_b, log_dur);

  // ---- length regulator ----
  build_p_k<<<dim3(513, BB), dim3(256), 0, stream>>>(x, cum, pos_alpha, peT, Pb);

  // ---- pitch predictor (5 layers, MT=128, 8 waves 2x4, 3-deep pipeline) ----
  constexpr int LDS_PP = gemm_lds(128, 5, 384, 4, 5);   // 140.5 KB
  gemm_conv_ln<512, 384, 5, 128, 2, 4, 2, false, true>
      <<<dim3(16, BB), dim3(512), LDS_PP, stream>>>(
          Pb, pwpp0, pp_b, pp_g, pp_beta, ppA, nullptr, MAX_LEN);
  gemm_conv_ln<384, 384, 5, 128, 2, 4, 2, false, true>
      <<<dim3(16, BB), dim3(512), LDS_PP, stream>>>(
          ppA, pwppr + 0 * (5 * 384 * 384),
          pp_b + 384, pp_g + 384, pp_beta + 384, ppB, nullptr, MAX_LEN);
  gemm_conv_ln<384, 384, 5, 128, 2, 4, 2, false, true>
      <<<dim3(16, BB), dim3(512), LDS_PP, stream>>>(
          ppB, pwppr + 1 * (5 * 384 * 384),
          pp_b + 768, pp_g + 768, pp_beta + 768, ppA, nullptr, MAX_LEN);
  gemm_conv_ln<384, 384, 5, 128, 2, 4, 2, false, true>
      <<<dim3(16, BB), dim3(512), LDS_PP, stream>>>(
          ppA, pwppr + 2 * (5 * 384 * 384),
          pp_b + 1152, pp_g + 1152, pp_beta + 1152, ppB, nullptr, MAX_LEN);
  gemm_conv_ln<384, 384, 5, 128, 2, 4, 0, false, true>
      <<<dim3(16, BB), dim3(512), LDS_PP, stream>>>(
          ppB, pwppr + 3 * (5 * 384 * 384),
          pp_b + 1536, pp_g + 1536, pp_beta + 1536, pfin, nullptr, MAX_LEN);

  // ---- final fused head ----
  final_head_k<<<dim3(MAX_LEN / 4, BB), dim3(256), 0, stream>>>(
      pfin, x, cum, pp_lin_w, pp_lin_b, pitch_bins, pitch_emb, out0, pitch_pred);
}